// Round 2
// baseline (1365.700 us; speedup 1.0000x reference)
//
#include <hip/hip_runtime.h>
#include <hip/hip_bf16.h>

#define B_SZ  4
#define T_SEQ 4096
#define NE    2048
#define HD    128

// ---------------- K1: QKV projection ----------------
// x[16384][2048] fp32 @ {Wq,Wk,Wv}[2048][128] fp32 -> q,k,v fp32 [16384][128] in ws
__global__ __launch_bounds__(256) void qkv_proj_kernel(
    const float* __restrict__ x,
    const float* __restrict__ Wq,
    const float* __restrict__ Wk,
    const float* __restrict__ Wv,
    float* __restrict__ qf, float* __restrict__ kf, float* __restrict__ vf)
{
    // x tile transposed: [k][row], fp32, padded to 36 (144B rows keep float4 16B-aligned)
    __shared__ __align__(16) float xT[32][36];

    const int tid  = threadIdx.x;
    const int h    = tid & 127;
    const int rg   = tid >> 7;            // 0,1 -> rows rg*16..rg*16+15
    const int row0 = blockIdx.x * 32;

    float acc[16][3];
    #pragma unroll
    for (int i = 0; i < 16; i++)
        #pragma unroll
        for (int m = 0; m < 3; m++) acc[i][m] = 0.0f;

    const int sr = tid >> 3;              // staging row 0..31
    const int sc = (tid & 7) << 2;        // staging col 0,4,..,28

    for (int kc = 0; kc < NE; kc += 32) {
        __syncthreads();
        {
            const float4 u = *(const float4*)(x + (size_t)(row0 + sr) * NE + kc + sc);
            xT[sc + 0][sr] = u.x;
            xT[sc + 1][sr] = u.y;
            xT[sc + 2][sr] = u.z;
            xT[sc + 3][sr] = u.w;
        }
        __syncthreads();

        #pragma unroll 4
        for (int k = 0; k < 32; k++) {
            const float4 a0 = *(const float4*)&xT[k][rg * 16 + 0];
            const float4 a1 = *(const float4*)&xT[k][rg * 16 + 4];
            const float4 a2 = *(const float4*)&xT[k][rg * 16 + 8];
            const float4 a3 = *(const float4*)&xT[k][rg * 16 + 12];
            const float xv[16] = {a0.x, a0.y, a0.z, a0.w, a1.x, a1.y, a1.z, a1.w,
                                  a2.x, a2.y, a2.z, a2.w, a3.x, a3.y, a3.z, a3.w};
            const size_t wo = (size_t)(kc + k) * HD + h;
            const float wqv = Wq[wo];
            const float wkv = Wk[wo];
            const float wvv = Wv[wo];
            #pragma unroll
            for (int i = 0; i < 16; i++) {
                acc[i][0] = fmaf(xv[i], wqv, acc[i][0]);
                acc[i][1] = fmaf(xv[i], wkv, acc[i][1]);
                acc[i][2] = fmaf(xv[i], wvv, acc[i][2]);
            }
        }
    }

    #pragma unroll
    for (int i = 0; i < 16; i++) {
        const size_t o = (size_t)(row0 + rg * 16 + i) * HD + h;
        qf[o] = acc[i][0];
        kf[o] = acc[i][1];
        vf[o] = acc[i][2];
    }
}

// ---------------- K2: causal flash attention ----------------
// One block handles a composed Q-tile: 32 "low" rows (L0..L0+31, local 0..31)
// + 32 "high" rows (H0..H0+31, local 32..63) so causal work is ~constant/block.
__global__ __launch_bounds__(256) void attn_kernel(
    const float* __restrict__ qf,
    const float* __restrict__ kf,
    const float* __restrict__ vf,
    float* __restrict__ out)
{
    __shared__ float qT[HD][68];   // [h][local q], padded (272B rows, 16B-aligned f4)
    __shared__ float kT[HD][68];   // [h][key in tile]
    __shared__ float vS[64][132];  // [key in tile][h]
    __shared__ float pT[64][68];   // [key in tile][local q]

    const int b  = blockIdx.y;
    const int jb = blockIdx.x;             // 0..63
    const int L0 = jb * 32;
    const int H0 = T_SEQ - 32 * (jb + 1);

    const int tid = threadIdx.x;
    const int tq  = tid >> 4;              // 0..15 -> local q rows tq*4..+3
    const int tk  = tid & 15;              // S: keys tk*4..+3 ; O: h = tk*8..+7

    const bool isHigh = (tq >= 8);         // wave-uniform (waves 0,1 low; 2,3 high)
    const int  qbase  = isHigh ? (H0 + (tq - 8) * 4) : (L0 + tq * 4); // global row of i=0

    // stage Q tile (fp32)
    for (int idx = tid; idx < 64 * HD; idx += 256) {
        const int lq = idx >> 7;
        const int h  = idx & 127;
        const int grow = (lq < 32) ? (L0 + lq) : (H0 + lq - 32);
        qT[h][lq] = qf[((size_t)b * T_SEQ + grow) * HD + h];
    }

    float m_i[4], l_i[4], o_acc[4][8];
    #pragma unroll
    for (int i = 0; i < 4; i++) {
        m_i[i] = -INFINITY;
        l_i[i] = 0.0f;
        #pragma unroll
        for (int c = 0; c < 8; c++) o_acc[i][c] = 0.0f;
    }

    const int   kmax  = H0 + 31;           // largest key any row in this block needs
    const float scale = 0.08838834764831845f;  // 1/sqrt(128)

    for (int s0 = 0; s0 <= kmax; s0 += 64) {
        __syncthreads();   // protect previous tile's LDS consumers
        for (int idx = tid; idx < 64 * HD; idx += 256) {
            const int kk = idx >> 7;
            const int h  = idx & 127;
            const size_t g = ((size_t)b * T_SEQ + s0 + kk) * HD + h;
            kT[h][kk] = kf[g];
            vS[kk][h] = vf[g];
        }
        __syncthreads();

        const bool act = isHigh || (s0 <= L0 + 31);
        float alpha[4] = {1.f, 1.f, 1.f, 1.f};

        if (act) {
            float s[4][4];
            #pragma unroll
            for (int i = 0; i < 4; i++)
                #pragma unroll
                for (int j2 = 0; j2 < 4; j2++) s[i][j2] = 0.0f;

            #pragma unroll 4
            for (int hh = 0; hh < HD; hh++) {
                const float4 qv = *(const float4*)&qT[hh][tq * 4];
                const float4 kv = *(const float4*)&kT[hh][tk * 4];
                s[0][0] = fmaf(qv.x, kv.x, s[0][0]);
                s[0][1] = fmaf(qv.x, kv.y, s[0][1]);
                s[0][2] = fmaf(qv.x, kv.z, s[0][2]);
                s[0][3] = fmaf(qv.x, kv.w, s[0][3]);
                s[1][0] = fmaf(qv.y, kv.x, s[1][0]);
                s[1][1] = fmaf(qv.y, kv.y, s[1][1]);
                s[1][2] = fmaf(qv.y, kv.z, s[1][2]);
                s[1][3] = fmaf(qv.y, kv.w, s[1][3]);
                s[2][0] = fmaf(qv.z, kv.x, s[2][0]);
                s[2][1] = fmaf(qv.z, kv.y, s[2][1]);
                s[2][2] = fmaf(qv.z, kv.z, s[2][2]);
                s[2][3] = fmaf(qv.z, kv.w, s[2][3]);
                s[3][0] = fmaf(qv.w, kv.x, s[3][0]);
                s[3][1] = fmaf(qv.w, kv.y, s[3][1]);
                s[3][2] = fmaf(qv.w, kv.z, s[3][2]);
                s[3][3] = fmaf(qv.w, kv.w, s[3][3]);
            }

            #pragma unroll
            for (int i = 0; i < 4; i++) {
                float sv[4];
                #pragma unroll
                for (int j2 = 0; j2 < 4; j2++) {
                    float t = s[i][j2] * scale;
                    if (s0 + tk * 4 + j2 > qbase + i) t = -INFINITY;
                    sv[j2] = t;
                }
                float rm = fmaxf(fmaxf(sv[0], sv[1]), fmaxf(sv[2], sv[3]));
                #pragma unroll
                for (int off = 1; off < 16; off <<= 1)
                    rm = fmaxf(rm, __shfl_xor(rm, off));
                const float mnew = fmaxf(m_i[i], rm);
                alpha[i] = __expf(m_i[i] - mnew);    // 0 when m_i=-inf (first tile)
                m_i[i] = mnew;
                float rs = 0.0f;
                #pragma unroll
                for (int j2 = 0; j2 < 4; j2++) {
                    const float p = __expf(sv[j2] - mnew);   // 0 for masked
                    rs += p;
                    pT[tk * 4 + j2][tq * 4 + i] = p;
                }
                #pragma unroll
                for (int off = 1; off < 16; off <<= 1)
                    rs += __shfl_xor(rs, off);
                l_i[i] = l_i[i] * alpha[i] + rs;
            }
        }
        __syncthreads();   // pT visible to O-phase (all threads reach this)

        if (act) {
            #pragma unroll
            for (int i = 0; i < 4; i++)
                #pragma unroll
                for (int c = 0; c < 8; c++) o_acc[i][c] *= alpha[i];

            #pragma unroll 2
            for (int kk = 0; kk < 64; kk++) {
                const float4 pv = *(const float4*)&pT[kk][tq * 4];
                const float4 va = *(const float4*)&vS[kk][tk * 8];
                const float4 vb = *(const float4*)&vS[kk][tk * 8 + 4];
                const float pc[4] = {pv.x, pv.y, pv.z, pv.w};
                const float vc[8] = {va.x, va.y, va.z, va.w, vb.x, vb.y, vb.z, vb.w};
                #pragma unroll
                for (int i = 0; i < 4; i++)
                    #pragma unroll
                    for (int c = 0; c < 8; c++)
                        o_acc[i][c] = fmaf(pc[i], vc[c], o_acc[i][c]);
            }
        }
    }

    // epilogue: out[b][row][h] = o / l   (every row has >=1 valid key, l >= 1)
    #pragma unroll
    for (int i = 0; i < 4; i++) {
        const float inv = 1.0f / l_i[i];
        const size_t o = ((size_t)b * T_SEQ + qbase + i) * HD + tk * 8;
        #pragma unroll
        for (int c = 0; c < 8; c++)
            out[o + c] = o_acc[i][c] * inv;
    }
}

extern "C" void kernel_launch(void* const* d_in, const int* in_sizes, int n_in,
                              void* d_out, int out_size, void* d_ws, size_t ws_size,
                              hipStream_t stream) {
    const float* x  = (const float*)d_in[0];
    const float* Wq = (const float*)d_in[1];
    const float* Wk = (const float*)d_in[2];
    const float* Wv = (const float*)d_in[3];

    const size_t nrows = (size_t)B_SZ * T_SEQ;        // 16384
    float* qf = (float*)d_ws;                          // 8 MB
    float* kf = qf + nrows * HD;                       // 8 MB
    float* vf = kf + nrows * HD;                       // 8 MB  (24 MB total)

    qkv_proj_kernel<<<dim3(nrows / 32), dim3(256), 0, stream>>>(x, Wq, Wk, Wv, qf, kf, vf);
    attn_kernel<<<dim3(T_SEQ / 64, B_SZ), dim3(256), 0, stream>>>(
        qf, kf, vf, (float*)d_out);
}

// Round 3
// 419.732 us; speedup vs baseline: 3.2537x; 3.2537x over previous
//
#include <hip/hip_runtime.h>
#include <hip/hip_bf16.h>

#define B_SZ  4
#define T_SEQ 4096
#define NE    2048
#define HD    128
#define NROWS (B_SZ * T_SEQ)   // 16384

typedef __attribute__((ext_vector_type(4))) float f32x4;
typedef __attribute__((ext_vector_type(8))) short s16x8;

__device__ __forceinline__ ushort f2bf(float f) {
    __hip_bfloat16 h = __float2bfloat16(f);
    return *reinterpret_cast<ushort*>(&h);
}
__device__ __forceinline__ unsigned int pk2(float a, float b) {
    return (unsigned int)f2bf(a) | ((unsigned int)f2bf(b) << 16);
}

// ---------------- K0: W fp32 [2048][128] -> wt bf16 [384][2048] (B^T layout) ---------
__global__ __launch_bounds__(256) void wconv_kernel(
    const float* __restrict__ Wq, const float* __restrict__ Wk,
    const float* __restrict__ Wv, ushort* __restrict__ wt)
{
    __shared__ __align__(16) ushort tr[128][80];   // rows 160B: 16B-aligned b128
    const int mat = blockIdx.y;
    const int k0  = blockIdx.x * 64;
    const float* W = (mat == 0) ? Wq : (mat == 1) ? Wk : Wv;
    const int tid = threadIdx.x;

    #pragma unroll
    for (int p = 0; p < 32; p++) {
        const int idx = p * 256 + tid;
        const int k = idx >> 7, h = idx & 127;
        tr[h][k] = f2bf(W[(size_t)(k0 + k) * HD + h]);
    }
    __syncthreads();
    const int h = tid >> 1, half = tid & 1;
    const uint4* src = (const uint4*)&tr[h][half * 32];
    uint4* dst = (uint4*)(wt + (size_t)(mat * HD + h) * NE + k0 + half * 32);
    #pragma unroll
    for (int j = 0; j < 4; j++) dst[j] = src[j];
}

// ---------------- K1: qkv = x @ [Wq|Wk|Wv], MFMA bf16 ----------------
// block: 64 rows x 384 cols; wave w: all 4 m-tiles x 6 n-tiles (cols w*96..+95)
// outputs: q_b,k_b bf16 [row][h]; v transposed vt bf16 [h][row]
__global__ __launch_bounds__(256) void qkv_kernel(
    const float* __restrict__ x, const ushort* __restrict__ wt,
    ushort* __restrict__ q_b, ushort* __restrict__ k_b, ushort* __restrict__ vt)
{
    __shared__ __align__(16) ushort xa[2][64][72];  // [buf][row][k], 144B rows (2-way free)

    const int tid  = threadIdx.x;
    const int wave = tid >> 6, lane = tid & 63;
    const int nn   = lane & 15, quad = lane >> 4;
    const int rows0 = blockIdx.x * 64;
    const int c0    = wave * 96;

    f32x4 acc[4][6];
    #pragma unroll
    for (int mt = 0; mt < 4; mt++)
        #pragma unroll
        for (int nt = 0; nt < 6; nt++) acc[mt][nt] = (f32x4){0.f, 0.f, 0.f, 0.f};

    // staging: thread -> (row, 16-wide k chunk)
    const int srow = tid >> 2, skq = tid & 3;
    const float* xp = x + (size_t)(rows0 + srow) * NE + skq * 16;

    float4 xr[4];
    auto load_x = [&](int kc) {
        #pragma unroll
        for (int j = 0; j < 4; j++) xr[j] = *(const float4*)(xp + kc + j * 4);
    };
    auto write_x = [&](int buf) {
        uint4 w0, w1;
        w0.x = pk2(xr[0].x, xr[0].y); w0.y = pk2(xr[0].z, xr[0].w);
        w0.z = pk2(xr[1].x, xr[1].y); w0.w = pk2(xr[1].z, xr[1].w);
        w1.x = pk2(xr[2].x, xr[2].y); w1.y = pk2(xr[2].z, xr[2].w);
        w1.z = pk2(xr[3].x, xr[3].y); w1.w = pk2(xr[3].z, xr[3].w);
        *(uint4*)&xa[buf][srow][skq * 16]     = w0;
        *(uint4*)&xa[buf][srow][skq * 16 + 8] = w1;
    };

    load_x(0);
    write_x(0);

    for (int t = 0; t < 32; t++) {
        const int kc = t * 64;
        if (t + 1 < 32) load_x(kc + 64);
        __syncthreads();
        const int cb = t & 1;
        #pragma unroll
        for (int ks = 0; ks < 2; ks++) {
            s16x8 af[4], bf[6];
            #pragma unroll
            for (int mt = 0; mt < 4; mt++)
                af[mt] = *(const s16x8*)&xa[cb][mt * 16 + nn][ks * 32 + quad * 8];
            #pragma unroll
            for (int nt = 0; nt < 6; nt++)
                bf[nt] = *(const s16x8*)&wt[(size_t)(c0 + nt * 16 + nn) * NE + kc + ks * 32 + quad * 8];
            #pragma unroll
            for (int mt = 0; mt < 4; mt++)
                #pragma unroll
                for (int nt = 0; nt < 6; nt++)
                    acc[mt][nt] = __builtin_amdgcn_mfma_f32_16x16x32_bf16(
                        af[mt], bf[nt], acc[mt][nt], 0, 0, 0);
        }
        if (t + 1 < 32) write_x((t + 1) & 1);
    }

    // epilogue: D row = quad*4+reg (+mt*16), col = nn (+nt*16)
    #pragma unroll
    for (int mt = 0; mt < 4; mt++)
        #pragma unroll
        for (int nt = 0; nt < 6; nt++) {
            const int c = c0 + nt * 16 + nn;
            #pragma unroll
            for (int r = 0; r < 4; r++) {
                const int grow = rows0 + mt * 16 + quad * 4 + r;
                const ushort v = f2bf(acc[mt][nt][r]);
                if (c < 128)       q_b[(size_t)grow * HD + c] = v;
                else if (c < 256)  k_b[(size_t)grow * HD + (c - 128)] = v;
                else               vt[(size_t)(c - 256) * NROWS + grow] = v;
            }
        }
}

// ---------------- K2: causal flash attention, MFMA bf16 ----------------
// block = 64 composite q rows (32 low + 32 high); wave = 16 q rows.
__global__ __launch_bounds__(256) void attn_kernel(
    const ushort* __restrict__ q_b, const ushort* __restrict__ k_b,
    const ushort* __restrict__ vt, float* __restrict__ out)
{
    __shared__ __align__(16) ushort kT[2][64][136];  // [buf][key][h], 272B rows
    __shared__ __align__(16) ushort vT[2][128][72];  // [buf][h][key], 144B rows
    __shared__ __align__(16) ushort pT[64][72];      // [q local][key], wave-private rows

    const int b  = blockIdx.y;
    const int jb = blockIdx.x;                  // 0..63
    const int L0 = jb * 32;
    const int H0 = T_SEQ - 32 * (jb + 1);

    const int tid  = threadIdx.x;
    const int wave = tid >> 6, lane = tid & 63;
    const int nn   = lane & 15, quad = lane >> 4;
    const int qrow0 = (wave < 2) ? (L0 + wave * 16) : (H0 + (wave - 2) * 16);
    const size_t bT = (size_t)b * T_SEQ;

    // Q fragments (A-layout), held in registers for the whole kernel
    s16x8 qfrag[4];
    #pragma unroll
    for (int ks = 0; ks < 4; ks++)
        qfrag[ks] = *(const s16x8*)&q_b[(bT + qrow0 + nn) * HD + ks * 32 + quad * 8];

    const int skey = tid >> 4;            // 0..15
    const int shw  = (tid & 15) * 8;
    const int svh  = tid >> 3;            // 0..31
    const int svk  = (tid & 7) * 8;

    uint4 kr[4], vr[4];
    auto load_stage = [&](int s0) {
        #pragma unroll
        for (int p = 0; p < 4; p++)
            kr[p] = *(const uint4*)&k_b[(bT + s0 + p * 16 + skey) * HD + shw];
        #pragma unroll
        for (int p = 0; p < 4; p++)
            vr[p] = *(const uint4*)&vt[(size_t)(p * 32 + svh) * NROWS + bT + s0 + svk];
    };
    auto write_stage = [&](int buf) {
        #pragma unroll
        for (int p = 0; p < 4; p++) *(uint4*)&kT[buf][p * 16 + skey][shw] = kr[p];
        #pragma unroll
        for (int p = 0; p < 4; p++) *(uint4*)&vT[buf][p * 32 + svh][svk] = vr[p];
    };

    f32x4 o_acc[8];
    float m_i[4], l_i[4];
    #pragma unroll
    for (int nt = 0; nt < 8; nt++) o_acc[nt] = (f32x4){0.f, 0.f, 0.f, 0.f};
    #pragma unroll
    for (int r = 0; r < 4; r++) { m_i[r] = -INFINITY; l_i[r] = 0.0f; }

    const float scale = 0.08838834764831845f;   // 1/sqrt(128)
    const int ntiles = (H0 + 95) >> 6;          // covers keys 0..H0+31

    load_stage(0);
    write_stage(0);

    for (int t = 0; t < ntiles; t++) {
        const int s0 = t * 64;
        if (t + 1 < ntiles) load_stage(s0 + 64);
        __syncthreads();
        const int cb = t & 1;
        const bool act = (wave >= 2) || (s0 <= L0 + 31);   // wave-uniform

        if (act) {
            // S = Q K^T  (4 key n-tiles)
            f32x4 sa[4];
            #pragma unroll
            for (int n = 0; n < 4; n++) sa[n] = (f32x4){0.f, 0.f, 0.f, 0.f};
            #pragma unroll
            for (int ks = 0; ks < 4; ks++)
                #pragma unroll
                for (int n = 0; n < 4; n++) {
                    const s16x8 kb = *(const s16x8*)&kT[cb][n * 16 + nn][ks * 32 + quad * 8];
                    sa[n] = __builtin_amdgcn_mfma_f32_16x16x32_bf16(qfrag[ks], kb, sa[n], 0, 0, 0);
                }

            // online softmax (C-layout: col=nn+16n, rows quad*4+r)
            float alpha[4], pv[4][4];
            #pragma unroll
            for (int r = 0; r < 4; r++) {
                const int grow = qrow0 + quad * 4 + r;
                float sv[4];
                #pragma unroll
                for (int n = 0; n < 4; n++) {
                    float s = sa[n][r] * scale;
                    if (s0 + n * 16 + nn > grow) s = -INFINITY;
                    sv[n] = s;
                }
                float rm = fmaxf(fmaxf(sv[0], sv[1]), fmaxf(sv[2], sv[3]));
                #pragma unroll
                for (int off = 1; off < 16; off <<= 1) rm = fmaxf(rm, __shfl_xor(rm, off));
                const float mnew = fmaxf(m_i[r], rm);
                alpha[r] = __expf(m_i[r] - mnew);
                m_i[r] = mnew;
                float rs = 0.0f;
                #pragma unroll
                for (int n = 0; n < 4; n++) {
                    const float p = __expf(sv[n] - mnew);
                    pv[n][r] = p;
                    rs += p;
                }
                #pragma unroll
                for (int off = 1; off < 16; off <<= 1) rs += __shfl_xor(rs, off);
                l_i[r] = l_i[r] * alpha[r] + rs;
            }

            // P -> LDS (wave-private rows), bf16
            #pragma unroll
            for (int n = 0; n < 4; n++)
                #pragma unroll
                for (int r = 0; r < 4; r++)
                    pT[wave * 16 + quad * 4 + r][n * 16 + nn] = f2bf(pv[n][r]);

            // rescale O
            #pragma unroll
            for (int nt = 0; nt < 8; nt++) {
                o_acc[nt][0] *= alpha[0];
                o_acc[nt][1] *= alpha[1];
                o_acc[nt][2] *= alpha[2];
                o_acc[nt][3] *= alpha[3];
            }

            // O += P V  (A = P from pT, B = V from vT)
            s16x8 pf[2];
            #pragma unroll
            for (int kst = 0; kst < 2; kst++)
                pf[kst] = *(const s16x8*)&pT[wave * 16 + nn][kst * 32 + quad * 8];
            #pragma unroll
            for (int nt = 0; nt < 8; nt++)
                #pragma unroll
                for (int kst = 0; kst < 2; kst++) {
                    const s16x8 vb = *(const s16x8*)&vT[cb][nt * 16 + nn][kst * 32 + quad * 8];
                    o_acc[nt] = __builtin_amdgcn_mfma_f32_16x16x32_bf16(pf[kst], vb, o_acc[nt], 0, 0, 0);
                }
        }
        if (t + 1 < ntiles) write_stage((t + 1) & 1);
    }

    // epilogue: out fp32 [b][row][h]
    #pragma unroll
    for (int r = 0; r < 4; r++) {
        const float inv = 1.0f / l_i[r];
        float* op = out + (bT + qrow0 + quad * 4 + r) * HD + nn;
        #pragma unroll
        for (int nt = 0; nt < 8; nt++) op[nt * 16] = o_acc[nt][r] * inv;
    }
}

extern "C" void kernel_launch(void* const* d_in, const int* in_sizes, int n_in,
                              void* d_out, int out_size, void* d_ws, size_t ws_size,
                              hipStream_t stream) {
    const float* x  = (const float*)d_in[0];
    const float* Wq = (const float*)d_in[1];
    const float* Wk = (const float*)d_in[2];
    const float* Wv = (const float*)d_in[3];

    ushort* q_b = (ushort*)d_ws;                       // 4 MB
    ushort* k_b = q_b + (size_t)NROWS * HD;            // 4 MB
    ushort* vtp = k_b + (size_t)NROWS * HD;            // 4 MB (v transposed [h][row])
    ushort* wt  = vtp + (size_t)HD * NROWS;            // 1.5 MB ([384][2048] bf16)

    wconv_kernel<<<dim3(32, 3), dim3(256), 0, stream>>>(Wq, Wk, Wv, wt);
    qkv_kernel<<<dim3(256), dim3(256), 0, stream>>>(x, wt, q_b, k_b, vtp);
    attn_kernel<<<dim3(64, B_SZ), dim3(256), 0, stream>>>(q_b, k_b, vtp, (float*)d_out);
}